// Round 18
// baseline (351.058 us; speedup 1.0000x reference)
//
#include <hip/hip_runtime.h>
#include <hip/hip_bf16.h>

#define ROWS 8192   // B*M
#define DD   1024
#define HH   16
#define HD   64
#define FF   4096

typedef __attribute__((ext_vector_type(4))) float f32x4;
typedef __attribute__((ext_vector_type(8))) __bf16 bf16x8;

static __device__ __forceinline__ unsigned short f2bf(float f) {
  unsigned u = __float_as_uint(f);
  u += 0x7fffu + ((u >> 16) & 1u);
  return (unsigned short)(u >> 16);
}

static __device__ __forceinline__ float bf2f(unsigned short u) {
  return __uint_as_float(((unsigned)u) << 16);
}

static __device__ __forceinline__ unsigned cvtpk_bf16(float lo, float hi) {
  unsigned r;
  asm("v_cvt_pk_bf16_f32 %0, %1, %2" : "=v"(r) : "v"(lo), "v"(hi));
  return r;
}

static __device__ __forceinline__ f32x4 mfma16(bf16x8 a, bf16x8 b, f32x4 c) {
  return __builtin_amdgcn_mfma_f32_16x16x32_bf16(a, b, c, 0, 0, 0);
}

#define GLOAD16(gp, lp) __builtin_amdgcn_global_load_lds( \
    (__attribute__((address_space(1))) void*)(gp), \
    (__attribute__((address_space(3))) void*)(lp), 16, 0, 0)

// ============ prep: casts (h, hall) + all 6 weight transposes, one launch ====
__global__ __launch_bounds__(256) void prep_k(
    const float* __restrict__ h, const float* __restrict__ hall,
    const float* __restrict__ Wq, const float* __restrict__ Wk,
    const float* __restrict__ Wv, const float* __restrict__ Wo,
    const float* __restrict__ W1, const float* __restrict__ W2,
    unsigned short* __restrict__ hb, unsigned short* __restrict__ hab,
    unsigned short* __restrict__ wqt, unsigned short* __restrict__ wkvt,
    unsigned short* __restrict__ wot, unsigned short* __restrict__ w1t,
    unsigned short* __restrict__ w2t) {
  __shared__ unsigned short tile[64][66];
  const int bid = blockIdx.x;
  const int tid = threadIdx.x;

  if (bid < 16384) {  // casts: 1024 f32 per block
    const float* src = (bid < 8192) ? h : hall;
    unsigned short* dst = (bid < 8192) ? hb : hab;
    int i = (bid & 8191) * 256 + tid;
    float4 v = ((const float4*)src)[i];
    ushort4 o;
    o.x = f2bf(v.x); o.y = f2bf(v.y); o.z = f2bf(v.z); o.w = f2bf(v.w);
    ((ushort4*)dst)[i] = o;
    return;
  }

  int r = bid - 16384;
  const float* src; unsigned short* dst; int R, C, bx, by;
  if (r < 1024) {           // Wq,Wk,Wv,Wo: 1024x1024, 16x16 tiles of 64x64
    int which = r >> 8, idx = r & 255;
    R = C = 1024; bx = idx & 15; by = idx >> 4;
    if (which == 0) { src = Wq; dst = wqt; }
    else if (which == 1) { src = Wk; dst = wkvt; }
    else if (which == 2) { src = Wv; dst = wkvt + (size_t)DD * DD; }
    else { src = Wo; dst = wot; }
  } else if (r < 2048) {    // W1: 1024x4096
    int idx = r - 1024;
    R = 1024; C = 4096; bx = idx & 63; by = idx >> 6;
    src = W1; dst = w1t;
  } else {                  // W2: 4096x1024
    int idx = r - 2048;
    R = 4096; C = 1024; bx = idx & 15; by = idx >> 4;
    src = W2; dst = w2t;
  }
  const int col = tid & 63, q4 = tid >> 6;   // 64 x 4
  #pragma unroll
  for (int i = 0; i < 16; ++i) {
    int rr = q4 + i * 4;
    tile[rr][col] = f2bf(src[(size_t)(by * 64 + rr) * C + bx * 64 + col]);
  }
  __syncthreads();
  #pragma unroll
  for (int i = 0; i < 16; ++i) {
    int c = q4 + i * 4;
    dst[(size_t)(bx * 64 + c) * R + by * 64 + col] = tile[col][c];
  }
}

// ============ GEMM body (device fn): BM x 256 tile, BK=64, 8 waves. ==========
// BM=256: 4-phase, ONE barrier/phase (R14 proven). BM=128: 2-phase dbuf.
// MODE 0: bf16 out  1: f32 out  2: bf16 out +bias +relu  3: f32 out +bias
// MODE 4: split epilogue (K row-major + V^T transposed)
// MODE 5 (KS=2): BOTH k-halves bf16; bias deferred to LN2.
template <int BM, int MODE, int KS = 1>
static __device__ __forceinline__ void gemm_body(
    char* ldsA, char* ldsB,
    const unsigned short* __restrict__ A, const unsigned short* __restrict__ BT,
    const float* __restrict__ bias, void* __restrict__ Cout, void* __restrict__ Cout2,
    int Ni, int Ki, int nbx, int wg, int nwg) {
  constexpr int MR = BM / 32;

  const int tid  = threadIdx.x;
  const int lane = tid & 63;
  const int wid  = tid >> 6;
  const int wm   = wid >> 2;
  const int wn   = wid & 3;
  const int lr   = lane & 15;
  const int kq   = lane >> 4;
  const int axor = (lr & 7) << 4;

  const int cpx = nwg >> 3;
  const int swz = (wg & 7) * cpx + (wg >> 3);
  const int perk = nwg / KS;
  const int kh   = swz / perk;
  const int swzr = swz % perk;
  const int bx = swzr % nbx, by = swzr / nbx;
  const int brow = by * BM, bcol = bx * 256;
  const int Kc   = Ki / KS;
  const int kbase = kh * Kc;

  f32x4 acc[MR][4] = {};
  const int NT = Kc >> 6;

  if constexpr (BM == 256) {
    const size_t loff = (size_t)(lane >> 3) * Ki + ((lane & 7) ^ (lane >> 3)) * 8;
    const unsigned short* Ab = A + (size_t)brow * Ki + kbase;
    const unsigned short* Bb = BT + (size_t)bcol * Ki + kbase;

    // chunk qc: A rows [qc*32,+32) u [128+qc*32,+32); B rows [qc*64,+64)
    auto stage2 = [&](int qc, int u, int db) {
      const int ra = ((wid & 4) << 5) + qc * 32 + (wid & 3) * 8;
      GLOAD16(Ab + (size_t)ra * Ki + u * 64 + loff, ldsA + db * 32768 + ra * 128);
      const int rb = qc * 64 + wid * 8;
      GLOAD16(Bb + (size_t)rb * Ki + u * 64 + loff, ldsB + db * 32768 + rb * 128);
    };

    // prologue: tile0 (8 loads) + tile1 chunks 0..2 (6 loads)
    #pragma unroll
    for (int qc = 0; qc < 4; ++qc) stage2(qc, 0, 0);
    {
      const int u1 = (1 < NT) ? 1 : NT - 1;
      stage2(0, u1, 1); stage2(1, u1, 1); stage2(2, u1, 1);
    }
    asm volatile("s_waitcnt vmcnt(6)" ::: "memory");
    __builtin_amdgcn_s_barrier();
    __builtin_amdgcn_sched_barrier(0);

    #pragma unroll 1
    for (int t = 0; t < NT; ++t) {
      const int d = t & 1;
      const char* ab = ldsA + d * 32768;
      const char* bb = ldsB + d * 32768;
      bf16x8 bfv[4][2];
      #pragma unroll
      for (int q = 0; q < 4; ++q) {
        bf16x8 af[2][2];
        #pragma unroll
        for (int mm = 0; mm < 2; ++mm)
          #pragma unroll
          for (int ks = 0; ks < 2; ++ks)
            af[mm][ks] = *(const bf16x8*)(ab +
                (wm * 128 + (q * 2 + mm) * 16 + lr) * 128 +
                ((ks * 64 + kq * 16) ^ axor));
        if (q == 0) {
          #pragma unroll
          for (int n = 0; n < 4; ++n)
            #pragma unroll
            for (int ks = 0; ks < 2; ++ks)
              bfv[n][ks] = *(const bf16x8*)(bb +
                  (wn * 64 + n * 16 + lr) * 128 +
                  ((ks * 64 + kq * 16) ^ axor));
        }
        if (q == 0) {
          stage2(3, (t + 1 < NT) ? t + 1 : NT - 1, (t + 1) & 1);
        } else {
          stage2(q - 1, (t + 2 < NT) ? t + 2 : NT - 1, d);
        }
        __builtin_amdgcn_s_setprio(1);
        #pragma unroll
        for (int mm = 0; mm < 2; ++mm)
          #pragma unroll
          for (int n = 0; n < 4; ++n) {
            acc[q * 2 + mm][n] = mfma16(af[mm][0], bfv[n][0], acc[q * 2 + mm][n]);
            acc[q * 2 + mm][n] = mfma16(af[mm][1], bfv[n][1], acc[q * 2 + mm][n]);
          }
        __builtin_amdgcn_s_setprio(0);
        __builtin_amdgcn_sched_barrier(0);
        if (q == 3) asm volatile("s_waitcnt vmcnt(6)" ::: "memory");
        __builtin_amdgcn_s_barrier();
        __builtin_amdgcn_sched_barrier(0);
      }
    }
    asm volatile("s_waitcnt vmcnt(0)" ::: "memory");
  } else {
    const int srow = wid * 8 + (lane >> 3);
    const int scol = ((lane & 7) * 8) ^ ((srow & 7) << 3);
    size_t offA[BM / 64], offB[4];
    #pragma unroll
    for (int L = 0; L < BM / 64; ++L)
      offA[L] = (size_t)(brow + L * 64 + srow) * Ki + kbase + scol;
    #pragma unroll
    for (int L = 0; L < 4; ++L)
      offB[L] = (size_t)(bcol + L * 64 + srow) * Ki + kbase + scol;

    auto stage = [&](int t, int d) {
      #pragma unroll
      for (int L = 0; L < BM / 64; ++L)
        GLOAD16(A + offA[L] + t * 64, ldsA + d * (BM * 128) + L * 8192 + wid * 1024);
      #pragma unroll
      for (int L = 0; L < 4; ++L)
        GLOAD16(BT + offB[L] + t * 64, ldsB + d * 32768 + L * 8192 + wid * 1024);
    };

    stage(0, 0);
    stage(1, 1);

    #pragma unroll 1
    for (int t = 0; t < NT; ++t) {
      const int d = t & 1;
      asm volatile("s_waitcnt vmcnt(6)" ::: "memory");
      __builtin_amdgcn_s_barrier();
      __builtin_amdgcn_sched_barrier(0);

      const char* as = ldsA + d * (BM * 128);
      const char* bs = ldsB + d * 32768;
      #pragma unroll
      for (int kk = 0; kk < 2; ++kk) {
        bf16x8 af[MR], bfv[4];
        #pragma unroll
        for (int m = 0; m < MR; ++m)
          af[m] = *(const bf16x8*)(as +
              (wm * (BM / 2) + m * 16 + lr) * 128 + ((kk * 64 + kq * 16) ^ axor));
        #pragma unroll
        for (int n = 0; n < 4; ++n)
          bfv[n] = *(const bf16x8*)(bs +
              (wn * 64 + n * 16 + lr) * 128 + ((kk * 64 + kq * 16) ^ axor));
        #pragma unroll
        for (int m = 0; m < MR; ++m)
          #pragma unroll
          for (int n = 0; n < 4; ++n)
            acc[m][n] = mfma16(af[m], bfv[n], acc[m][n]);
      }

      asm volatile("s_waitcnt lgkmcnt(0)" ::: "memory");
      __builtin_amdgcn_s_barrier();
      __builtin_amdgcn_sched_barrier(0);
      const int ts = (t + 2 < NT) ? t + 2 : NT - 1;
      stage(ts, d);
    }
  }

  #pragma unroll
  for (int m = 0; m < MR; ++m) {
    #pragma unroll
    for (int n = 0; n < 4; ++n) {
      const int r0 = brow + wm * (BM / 2) + m * 16 + kq * 4;
      const int c  = bcol + wn * 64 + n * 16 + lr;
      if constexpr (MODE == 4) {
        if (c < 1024) {
          #pragma unroll
          for (int e = 0; e < 4; ++e)
            ((unsigned short*)Cout)[(size_t)(r0 + e) * 1024 + c] = f2bf(acc[m][n][e]);
        } else {
          const int cc = c - 1024;
          const int bq = r0 >> 10;
          const int tok = r0 & 1023;
          ushort4 pk;
          pk.x = f2bf(acc[m][n][0]); pk.y = f2bf(acc[m][n][1]);
          pk.z = f2bf(acc[m][n][2]); pk.w = f2bf(acc[m][n][3]);
          *(ushort4*)((unsigned short*)Cout2 + ((size_t)bq * 1024 + cc) * 1024 + tok) = pk;
        }
      } else if constexpr (MODE == 5) {
        unsigned short* o = (kh == 0) ? (unsigned short*)Cout : (unsigned short*)Cout2;
        #pragma unroll
        for (int e = 0; e < 4; ++e)
          o[(size_t)(r0 + e) * Ni + c] = f2bf(acc[m][n][e]);
      } else {
        const float bv = (MODE == 2 || MODE == 3) ? bias[c] : 0.0f;
        #pragma unroll
        for (int e = 0; e < 4; ++e) {
          float v = acc[m][n][e] + bv;
          if (MODE == 2) v = fmaxf(v, 0.0f);
          if (MODE == 0 || MODE == 2)
            ((unsigned short*)Cout)[(size_t)(r0 + e) * Ni + c] = f2bf(v);
          else
            ((float*)Cout)[(size_t)(r0 + e) * Ni + c] = v;
        }
      }
    }
  }
}

template <int BM, int MODE, int KS = 1>
__global__ __launch_bounds__(512, 2) void gemm256(
    const unsigned short* __restrict__ A, const unsigned short* __restrict__ BT,
    const float* __restrict__ bias, void* __restrict__ Cout, void* __restrict__ Cout2,
    int Ni, int Ki, int nbx) {
  constexpr int ABYTES = 2 * BM * 64 * 2;
  __shared__ char lds[ABYTES + 65536];
  gemm_body<BM, MODE, KS>(lds, lds + ABYTES, A, BT, bias, Cout, Cout2,
                          Ni, Ki, nbx, (int)blockIdx.x, (int)gridDim.x);
}

// ---- merged QKV projections: blocks [0,256) = KV (BM=256 MODE4),
//      blocks [256,512) = Q (BM=128 MODE0). One dispatch packs the machine.
__global__ __launch_bounds__(512, 2) void qkv_k(
    const unsigned short* __restrict__ hb, const unsigned short* __restrict__ hab,
    const unsigned short* __restrict__ wqt, const unsigned short* __restrict__ wkvt,
    unsigned short* __restrict__ qb, unsigned short* __restrict__ kb,
    unsigned short* __restrict__ vTb) {
  __shared__ char lds[131072];
  if (blockIdx.x < 256)
    gemm_body<256, 4, 1>(lds, lds + 65536, hab, wkvt, nullptr, kb, vTb,
                         2048, 1024, 8, (int)blockIdx.x, 256);
  else
    gemm_body<128, 0, 1>(lds, lds + 32768, hb, wqt, nullptr, qb, nullptr,
                         1024, 1024, 4, (int)blockIdx.x - 256, 256);
}

// ---------------- flash attention v5: 256 q-rows/block, 2 groups/wave --------
// grid (bh=128, qb=4) = 512 blocks. __launch_bounds__(512,2): VGPR cap 256
// (R16's spill was the (512,4) occupancy-forced 64-VGPR ceiling); occupancy
// LDS-limited to 2 blocks/CU (64KB). Staging + barrier cost per q-row halves,
// K/V HBM refetch halves vs 128-row version.
__global__ __launch_bounds__(512, 2) void attn_k(
    const unsigned short* __restrict__ q, const unsigned short* __restrict__ k,
    const unsigned short* __restrict__ vT, unsigned short* __restrict__ ctx) {
  __shared__ unsigned short Ks[2][64 * 64];   // 16KB
  __shared__ unsigned short Vt[2][64 * 64];   // 16KB
  __shared__ unsigned short Ps[8][32 * 64];   // 32KB: per-wave [32 q][64 tok]
  const int tid = threadIdx.x;
  const int lane = tid & 63;
  const int wid = tid >> 6;
  const int bh = blockIdx.x;                  // x = bh -> XCD affinity for K/V
  const int b = bh >> 4, h = bh & 15;
  const int qrow0 = blockIdx.y * 256 + wid * 32;
  const size_t tokbase = (size_t)b * 1024;
  const int lr = lane & 15, kq = lane >> 4;

  const int srow = tid >> 3;
  const int scol = ((tid & 7) * 8) ^ ((srow & 7) << 3);
  const unsigned short* kg = k + (tokbase + srow) * 1024 + h * 64 + scol;
  const unsigned short* vg = vT + ((size_t)(b * 16 + h) * 64 + srow) * 1024 + scol;
  const int ldst = tid * 16;

  auto stage = [&](int kt, int d) {
    GLOAD16(kg + (size_t)kt * 64 * 1024, (char*)Ks[d] + ldst);
    GLOAD16(vg + kt * 64, (char*)Vt[d] + ldst);
  };

  bf16x8 aq[2][2];
  #pragma unroll
  for (int g = 0; g < 2; ++g) {
    const unsigned short* qp =
        q + (tokbase + qrow0 + g * 16 + lr) * DD + h * 64 + kq * 8;
    aq[g][0] = *(const bf16x8*)qp;
    aq[g][1] = *(const bf16x8*)(qp + 32);
  }

  float l_acc[2] = {0.f, 0.f};
  f32x4 acc[2][4] = {};   // [g][db]: ctx[q=g*16+lr][d = db*16 + kq*4 + j]
  const float C = 0.125f * 1.4426950408889634f;
  const unsigned swp = (unsigned)((lr & 7) << 4);

  stage(0, 0);
  stage(1, 1);

  #pragma unroll 2
  for (int kt = 0; kt < 16; ++kt) {
    const int d = kt & 1;
    asm volatile("s_waitcnt vmcnt(2)" ::: "memory");
    __builtin_amdgcn_s_barrier();
    __builtin_amdgcn_sched_barrier(0);

    #pragma unroll
    for (int g = 0; g < 2; ++g) {
      // --- S^T = K Q^T for group g: sv[jb][j] = S[q][tok = jb*16+kq*4+j]
      f32x4 sv[4] = {};
      __builtin_amdgcn_s_setprio(1);
      #pragma unroll
      for (int jb = 0; jb < 4; ++jb)
        #pragma unroll
        for (int ks = 0; ks < 2; ++ks) {
          int row = jb * 16 + lr;
          bf16x8 ak = *(const bf16x8*)((const char*)Ks[d] +
              row * 128 + ((ks * 64 + kq * 16) ^ ((row & 7) << 4)));
          sv[jb] = mfma16(ak, aq[g][ks], sv[jb]);
        }
      __builtin_amdgcn_s_setprio(0);

      // --- exp (no-max), pack, store to P rows [g*16 + lr]
      const unsigned pbase = (unsigned)((g * 16 + lr) * 128);
      #pragma unroll
      for (int jb = 0; jb < 4; ++jb) {
        float p0 = exp2f(sv[jb][0] * C);
        float p1 = exp2f(sv[jb][1] * C);
        float p2 = exp2f(sv[jb][2] * C);
        float p3 = exp2f(sv[jb][3] * C);
        l_acc[g] += (p0 + p1) + (p2 + p3);
        uint2 w;
        w.x = cvtpk_bf16(p0, p1);
        w.y = cvtpk_bf16(p2, p3);
        unsigned off = pbase + (((unsigned)(jb * 32 + kq * 8)) ^ swp);
        *(uint2*)((char*)Ps[wid] + off) = w;
      }

      // --- ctx^T += V^T P^T for group g
      __builtin_amdgcn_s_setprio(1);
      #pragma unroll
      for (int ks = 0; ks < 2; ++ks) {
        bf16x8 ap = *(const bf16x8*)((const char*)Ps[wid] +
            (g * 16 + lr) * 128 + ((ks * 64 + kq * 16) ^ ((lr & 7) << 4)));
        #pragma unroll
        for (int db = 0; db < 4; ++db) {
          int dd = db * 16 + lr;
          bf16x8 bv = *(const bf16x8*)((const char*)Vt[d] +
              dd * 128 + ((ks * 64 + kq * 16) ^ ((dd & 7) << 4)));
          acc[g][db] = mfma16(bv, ap, acc[g][db]);
        }
      }
      __builtin_amdgcn_s_setprio(0);
    }

    asm volatile("s_waitcnt lgkmcnt(0)" ::: "memory");
    __builtin_amdgcn_s_barrier();
    __builtin_amdgcn_sched_barrier(0);
    const int ts = (kt + 2 < 16) ? kt + 2 : 15;
    stage(ts, d);
  }

  #pragma unroll
  for (int g = 0; g < 2; ++g) {
    float l = l_acc[g] + __shfl_xor(l_acc[g], 16);
    l += __shfl_xor(l, 32);
    const float inv = 1.0f / l;
    unsigned short* cp =
        ctx + (tokbase + qrow0 + g * 16 + lr) * DD + h * 64 + kq * 4;
    #pragma unroll
    for (int db = 0; db < 4; ++db) {
      ushort4 o;
      o.x = f2bf(acc[g][db][0] * inv);
      o.y = f2bf(acc[g][db][1] * inv);
      o.z = f2bf(acc[g][db][2] * inv);
      o.w = f2bf(acc[g][db][3] * inv);
      *(ushort4*)(cp + db * 16) = o;
    }
  }
}

// ---------------- LayerNorm(bf16 a + bf16 b) -> bf16 out ---------------------
__global__ __launch_bounds__(256) void ln_add_bb_k(
    const unsigned short* __restrict__ a, const unsigned short* __restrict__ b,
    const float* __restrict__ gamma, const float* __restrict__ beta,
    unsigned short* __restrict__ outb) {
  int row = blockIdx.x;
  int tid = threadIdx.x;
  size_t base = (size_t)row * 1024 + tid * 4;
  ushort4 va = *(const ushort4*)(a + base);
  ushort4 vb = *(const ushort4*)(b + base);
  float x[4] = {bf2f(va.x) + bf2f(vb.x), bf2f(va.y) + bf2f(vb.y),
                bf2f(va.z) + bf2f(vb.z), bf2f(va.w) + bf2f(vb.w)};
  float s = x[0] + x[1] + x[2] + x[3];
  float sq = x[0] * x[0] + x[1] * x[1] + x[2] * x[2] + x[3] * x[3];
  #pragma unroll
  for (int mk = 1; mk < 64; mk <<= 1) {
    s += __shfl_xor(s, mk);
    sq += __shfl_xor(sq, mk);
  }
  __shared__ float red[8];
  int wid = tid >> 6, lane = tid & 63;
  if (lane == 0) { red[wid] = s; red[4 + wid] = sq; }
  __syncthreads();
  s = red[0] + red[1] + red[2] + red[3];
  sq = red[4] + red[5] + red[6] + red[7];
  float mu = s * (1.0f / 1024.0f);
  float var = sq * (1.0f / 1024.0f) - mu * mu;
  float rs = rsqrtf(var + 1e-5f);
  float4 g = *(const float4*)(gamma + tid * 4);
  float4 be = *(const float4*)(beta + tid * 4);
  ushort4 ob;
  ob.x = f2bf((x[0] - mu) * rs * g.x + be.x);
  ob.y = f2bf((x[1] - mu) * rs * g.y + be.y);
  ob.z = f2bf((x[2] - mu) * rs * g.z + be.z);
  ob.w = f2bf((x[3] - mu) * rs * g.w + be.w);
  *(ushort4*)(outb + base) = ob;
}

// ---- LayerNorm(bf16 a + bf16 p0 + bf16 p1 + bias2) -> f32 out (FFN2 fused) --
__global__ __launch_bounds__(256) void ln3_k(
    const unsigned short* __restrict__ a, const unsigned short* __restrict__ p0,
    const unsigned short* __restrict__ p1, const float* __restrict__ b2,
    const float* __restrict__ gamma, const float* __restrict__ beta,
    float* __restrict__ outf) {
  int row = blockIdx.x;
  int tid = threadIdx.x;
  size_t base = (size_t)row * 1024 + tid * 4;
  ushort4 va = *(const ushort4*)(a + base);
  ushort4 v0 = *(const ushort4*)(p0 + base);
  ushort4 v1 = *(const ushort4*)(p1 + base);
  float4 bb = *(const float4*)(b2 + tid * 4);
  float x[4] = {bf2f(va.x) + bf2f(v0.x) + bf2f(v1.x) + bb.x,
                bf2f(va.y) + bf2f(v0.y) + bf2f(v1.y) + bb.y,
                bf2f(va.z) + bf2f(v0.z) + bf2f(v1.z) + bb.z,
                bf2f(va.w) + bf2f(v0.w) + bf2f(v1.w) + bb.w};
  float s = x[0] + x[1] + x[2] + x[3];
  float sq = x[0] * x[0] + x[1] * x[1] + x[2] * x[2] + x[3] * x[3];
  #pragma unroll
  for (int mk = 1; mk < 64; mk <<= 1) {
    s += __shfl_xor(s, mk);
    sq += __shfl_xor(sq, mk);
  }
  __shared__ float red[8];
  int wid = tid >> 6, lane = tid & 63;
  if (lane == 0) { red[wid] = s; red[4 + wid] = sq; }
  __syncthreads();
  s = red[0] + red[1] + red[2] + red[3];
  sq = red[4] + red[5] + red[6] + red[7];
  float mu = s * (1.0f / 1024.0f);
  float var = sq * (1.0f / 1024.0f) - mu * mu;
  float rs = rsqrtf(var + 1e-5f);
  float4 g = *(const float4*)(gamma + tid * 4);
  float4 be = *(const float4*)(beta + tid * 4);
  float4 o;
  o.x = (x[0] - mu) * rs * g.x + be.x;
  o.y = (x[1] - mu) * rs * g.y + be.y;
  o.z = (x[2] - mu) * rs * g.z + be.z;
  o.w = (x[3] - mu) * rs * g.w + be.w;
  *(float4*)(outf + base) = o;
}

// -----------------------------------------------------------------------------
extern "C" void kernel_launch(void* const* d_in, const int* in_sizes, int n_in,
                              void* d_out, int out_size, void* d_ws, size_t ws_size,
                              hipStream_t stream) {
  const float* h    = (const float*)d_in[0];
  const float* hall = (const float*)d_in[1];
  const float* Wq   = (const float*)d_in[2];
  const float* Wk   = (const float*)d_in[3];
  const float* Wv   = (const float*)d_in[4];
  const float* Wo   = (const float*)d_in[5];
  const float* W1   = (const float*)d_in[6];
  const float* b1   = (const float*)d_in[7];
  const float* W2   = (const float*)d_in[8];
  const float* b2   = (const float*)d_in[9];
  const float* g1   = (const float*)d_in[10];
  const float* be1  = (const float*)d_in[11];
  const float* g2   = (const float*)d_in[12];
  const float* be2  = (const float*)d_in[13];

  char* ws = (char*)d_ws;
  size_t off = 0;
  auto alloc = [&](size_t n) { size_t o = off; off += (n + 255) & ~(size_t)255; return o; };
  const size_t hb_o   = alloc((size_t)ROWS * DD * 2);
  const size_t hab_o  = alloc((size_t)ROWS * DD * 2);
  const size_t wqt_o  = alloc((size_t)DD * DD * 2);
  const size_t wkvt_o = alloc((size_t)DD * DD * 4);
  const size_t wot_o  = alloc((size_t)DD * DD * 2);
  const size_t w1t_o  = alloc((size_t)DD * FF * 2);
  const size_t w2t_o  = alloc((size_t)FF * DD * 2);
  const size_t qb_o   = alloc((size_t)ROWS * DD * 2);
  const size_t kb_o   = alloc((size_t)ROWS * DD * 2);
  const size_t vt_o   = alloc((size_t)ROWS * DD * 2);
  const size_t cx_o   = alloc((size_t)ROWS * DD * 2);
  const size_t h1b_o  = alloc((size_t)ROWS * DD * 2);
  const size_t fp1_o  = alloc((size_t)ROWS * DD * 2);

  unsigned short* hb   = (unsigned short*)(ws + hb_o);
  unsigned short* hab  = (unsigned short*)(ws + hab_o);
  unsigned short* wqt  = (unsigned short*)(ws + wqt_o);
  unsigned short* wkvt = (unsigned short*)(ws + wkvt_o);
  unsigned short* wot  = (unsigned short*)(ws + wot_o);
  unsigned short* w1t  = (unsigned short*)(ws + w1t_o);
  unsigned short* w2t  = (unsigned short*)(ws + w2t_o);
  unsigned short* qb   = (unsigned short*)(ws + qb_o);
  unsigned short* kb   = (unsigned short*)(ws + kb_o);
  unsigned short* vTb  = (unsigned short*)(ws + vt_o);
  unsigned short* cxb  = (unsigned short*)(ws + cx_o);
  unsigned short* h1b  = (unsigned short*)(ws + h1b_o);
  unsigned short* fp1b = (unsigned short*)(ws + fp1_o);
  // aliases (lifetime-disjoint):
  unsigned short* attn_ob = (unsigned short*)(ws + hab_o); // hab dead after KV-proj
  unsigned short* fp0b    = (unsigned short*)(ws + hb_o);  // hb dead after LN1
  unsigned short* ff1     = (unsigned short*)(ws + qb_o);  // 64MB over qb+kb+vT+cx
  float*          outf    = (float*)d_out;

  // 1. prep: casts + all weight transposes (one launch, 64x64 tiles)
  prep_k<<<dim3(16384 + 3072), 256, 0, stream>>>(
      h, hall, Wq, Wk, Wv, Wo, W1, W2, hb, hab, wqt, wkvt, wot, w1t, w2t);

  // 2. merged projections: KV (blocks 0-255) + Q (blocks 256-511)
  qkv_k<<<dim3(512), 512, 0, stream>>>(hb, hab, wqt, wkvt, qb, kb, vTb);

  // 3. attention (grid x = bh for XCD-affine K/V reuse; 256 q-rows/block)
  attn_k<<<dim3(128, 4), 512, 0, stream>>>(qb, kb, vTb, cxb);

  // 4. output projection (bf16 out over dead hab), then LN1 -> h1b (bf16 only)
  gemm256<128, 0><<<dim3(256), 512, 0, stream>>>(cxb, wot, nullptr, attn_ob, nullptr, DD, DD, 4);
  ln_add_bb_k<<<ROWS, 256, 0, stream>>>(hb, attn_ob, g1, be1, h1b);

  // 5. FFN: FFN1 direct; FFN2 split-K x2, both halves bf16 (bias in LN2)
  gemm256<256, 2>   <<<dim3(512), 512, 0, stream>>>(h1b, w1t, b1, ff1, nullptr, FF, DD, 16);
  gemm256<256, 5, 2><<<dim3(256), 512, 0, stream>>>(ff1, w2t, nullptr, fp0b, fp1b, DD, FF, 4);

  // 6. LN2: out = LN(h1b + ff2_p0 + ff2_p1 + b2)
  ln3_k<<<ROWS, 256, 0, stream>>>(h1b, fp0b, fp1b, b2, g2, be2, outf);
}

// Round 19
// 333.704 us; speedup vs baseline: 1.0520x; 1.0520x over previous
//
#include <hip/hip_runtime.h>
#include <hip/hip_bf16.h>

#define ROWS 8192   // B*M
#define DD   1024
#define HH   16
#define HD   64
#define FF   4096

typedef __attribute__((ext_vector_type(4))) float f32x4;
typedef __attribute__((ext_vector_type(8))) __bf16 bf16x8;

static __device__ __forceinline__ unsigned short f2bf(float f) {
  unsigned u = __float_as_uint(f);
  u += 0x7fffu + ((u >> 16) & 1u);
  return (unsigned short)(u >> 16);
}

static __device__ __forceinline__ float bf2f(unsigned short u) {
  return __uint_as_float(((unsigned)u) << 16);
}

static __device__ __forceinline__ unsigned cvtpk_bf16(float lo, float hi) {
  unsigned r;
  asm("v_cvt_pk_bf16_f32 %0, %1, %2" : "=v"(r) : "v"(lo), "v"(hi));
  return r;
}

static __device__ __forceinline__ f32x4 mfma16(bf16x8 a, bf16x8 b, f32x4 c) {
  return __builtin_amdgcn_mfma_f32_16x16x32_bf16(a, b, c, 0, 0, 0);
}

#define GLOAD16(gp, lp) __builtin_amdgcn_global_load_lds( \
    (__attribute__((address_space(1))) void*)(gp), \
    (__attribute__((address_space(3))) void*)(lp), 16, 0, 0)

// ============ prep: casts (h, hall) + all 6 weight transposes, one launch ====
__global__ __launch_bounds__(256) void prep_k(
    const float* __restrict__ h, const float* __restrict__ hall,
    const float* __restrict__ Wq, const float* __restrict__ Wk,
    const float* __restrict__ Wv, const float* __restrict__ Wo,
    const float* __restrict__ W1, const float* __restrict__ W2,
    unsigned short* __restrict__ hb, unsigned short* __restrict__ hab,
    unsigned short* __restrict__ wqt, unsigned short* __restrict__ wkvt,
    unsigned short* __restrict__ wot, unsigned short* __restrict__ w1t,
    unsigned short* __restrict__ w2t) {
  __shared__ unsigned short tile[64][66];
  const int bid = blockIdx.x;
  const int tid = threadIdx.x;

  if (bid < 16384) {  // casts: 1024 f32 per block
    const float* src = (bid < 8192) ? h : hall;
    unsigned short* dst = (bid < 8192) ? hb : hab;
    int i = (bid & 8191) * 256 + tid;
    float4 v = ((const float4*)src)[i];
    ushort4 o;
    o.x = f2bf(v.x); o.y = f2bf(v.y); o.z = f2bf(v.z); o.w = f2bf(v.w);
    ((ushort4*)dst)[i] = o;
    return;
  }

  int r = bid - 16384;
  const float* src; unsigned short* dst; int R, C, bx, by;
  if (r < 1024) {           // Wq,Wk,Wv,Wo: 1024x1024, 16x16 tiles of 64x64
    int which = r >> 8, idx = r & 255;
    R = C = 1024; bx = idx & 15; by = idx >> 4;
    if (which == 0) { src = Wq; dst = wqt; }
    else if (which == 1) { src = Wk; dst = wkvt; }
    else if (which == 2) { src = Wv; dst = wkvt + (size_t)DD * DD; }
    else { src = Wo; dst = wot; }
  } else if (r < 2048) {    // W1: 1024x4096
    int idx = r - 1024;
    R = 1024; C = 4096; bx = idx & 63; by = idx >> 6;
    src = W1; dst = w1t;
  } else {                  // W2: 4096x1024
    int idx = r - 2048;
    R = 4096; C = 1024; bx = idx & 15; by = idx >> 4;
    src = W2; dst = w2t;
  }
  const int col = tid & 63, q4 = tid >> 6;   // 64 x 4
  #pragma unroll
  for (int i = 0; i < 16; ++i) {
    int rr = q4 + i * 4;
    tile[rr][col] = f2bf(src[(size_t)(by * 64 + rr) * C + bx * 64 + col]);
  }
  __syncthreads();
  #pragma unroll
  for (int i = 0; i < 16; ++i) {
    int c = q4 + i * 4;
    dst[(size_t)(bx * 64 + c) * R + by * 64 + col] = tile[col][c];
  }
}

// ============ GEMM body (device fn): BM x 256 tile, BK=64, 8 waves. ==========
// BM=256: 4-phase, ONE barrier/phase (R14 proven). BM=128: 2-phase dbuf.
// MODE 0: bf16 out  1: f32 out  2: bf16 out +bias +relu  3: f32 out +bias
// MODE 4: split epilogue (K row-major + V^T transposed)
// MODE 5 (KS=2): BOTH k-halves bf16; bias deferred to LN2.
template <int BM, int MODE, int KS = 1>
static __device__ __forceinline__ void gemm_body(
    char* ldsA, char* ldsB,
    const unsigned short* __restrict__ A, const unsigned short* __restrict__ BT,
    const float* __restrict__ bias, void* __restrict__ Cout, void* __restrict__ Cout2,
    int Ni, int Ki, int nbx, int wg, int nwg) {
  constexpr int MR = BM / 32;

  const int tid  = threadIdx.x;
  const int lane = tid & 63;
  const int wid  = tid >> 6;
  const int wm   = wid >> 2;
  const int wn   = wid & 3;
  const int lr   = lane & 15;
  const int kq   = lane >> 4;
  const int axor = (lr & 7) << 4;

  const int cpx = nwg >> 3;
  const int swz = (wg & 7) * cpx + (wg >> 3);
  const int perk = nwg / KS;
  const int kh   = swz / perk;
  const int swzr = swz % perk;
  const int bx = swzr % nbx, by = swzr / nbx;
  const int brow = by * BM, bcol = bx * 256;
  const int Kc   = Ki / KS;
  const int kbase = kh * Kc;

  f32x4 acc[MR][4] = {};
  const int NT = Kc >> 6;

  if constexpr (BM == 256) {
    const size_t loff = (size_t)(lane >> 3) * Ki + ((lane & 7) ^ (lane >> 3)) * 8;
    const unsigned short* Ab = A + (size_t)brow * Ki + kbase;
    const unsigned short* Bb = BT + (size_t)bcol * Ki + kbase;

    // chunk qc: A rows [qc*32,+32) u [128+qc*32,+32); B rows [qc*64,+64)
    auto stage2 = [&](int qc, int u, int db) {
      const int ra = ((wid & 4) << 5) + qc * 32 + (wid & 3) * 8;
      GLOAD16(Ab + (size_t)ra * Ki + u * 64 + loff, ldsA + db * 32768 + ra * 128);
      const int rb = qc * 64 + wid * 8;
      GLOAD16(Bb + (size_t)rb * Ki + u * 64 + loff, ldsB + db * 32768 + rb * 128);
    };

    // prologue: tile0 (8 loads) + tile1 chunks 0..2 (6 loads)
    #pragma unroll
    for (int qc = 0; qc < 4; ++qc) stage2(qc, 0, 0);
    {
      const int u1 = (1 < NT) ? 1 : NT - 1;
      stage2(0, u1, 1); stage2(1, u1, 1); stage2(2, u1, 1);
    }
    asm volatile("s_waitcnt vmcnt(6)" ::: "memory");
    __builtin_amdgcn_s_barrier();
    __builtin_amdgcn_sched_barrier(0);

    #pragma unroll 1
    for (int t = 0; t < NT; ++t) {
      const int d = t & 1;
      const char* ab = ldsA + d * 32768;
      const char* bb = ldsB + d * 32768;
      bf16x8 bfv[4][2];
      #pragma unroll
      for (int q = 0; q < 4; ++q) {
        bf16x8 af[2][2];
        #pragma unroll
        for (int mm = 0; mm < 2; ++mm)
          #pragma unroll
          for (int ks = 0; ks < 2; ++ks)
            af[mm][ks] = *(const bf16x8*)(ab +
                (wm * 128 + (q * 2 + mm) * 16 + lr) * 128 +
                ((ks * 64 + kq * 16) ^ axor));
        if (q == 0) {
          #pragma unroll
          for (int n = 0; n < 4; ++n)
            #pragma unroll
            for (int ks = 0; ks < 2; ++ks)
              bfv[n][ks] = *(const bf16x8*)(bb +
                  (wn * 64 + n * 16 + lr) * 128 +
                  ((ks * 64 + kq * 16) ^ axor));
        }
        if (q == 0) {
          stage2(3, (t + 1 < NT) ? t + 1 : NT - 1, (t + 1) & 1);
        } else {
          stage2(q - 1, (t + 2 < NT) ? t + 2 : NT - 1, d);
        }
        __builtin_amdgcn_s_setprio(1);
        #pragma unroll
        for (int mm = 0; mm < 2; ++mm)
          #pragma unroll
          for (int n = 0; n < 4; ++n) {
            acc[q * 2 + mm][n] = mfma16(af[mm][0], bfv[n][0], acc[q * 2 + mm][n]);
            acc[q * 2 + mm][n] = mfma16(af[mm][1], bfv[n][1], acc[q * 2 + mm][n]);
          }
        __builtin_amdgcn_s_setprio(0);
        __builtin_amdgcn_sched_barrier(0);
        if (q == 3) asm volatile("s_waitcnt vmcnt(6)" ::: "memory");
        __builtin_amdgcn_s_barrier();
        __builtin_amdgcn_sched_barrier(0);
      }
    }
    asm volatile("s_waitcnt vmcnt(0)" ::: "memory");
  } else {
    const int srow = wid * 8 + (lane >> 3);
    const int scol = ((lane & 7) * 8) ^ ((srow & 7) << 3);
    size_t offA[BM / 64], offB[4];
    #pragma unroll
    for (int L = 0; L < BM / 64; ++L)
      offA[L] = (size_t)(brow + L * 64 + srow) * Ki + kbase + scol;
    #pragma unroll
    for (int L = 0; L < 4; ++L)
      offB[L] = (size_t)(bcol + L * 64 + srow) * Ki + kbase + scol;

    auto stage = [&](int t, int d) {
      #pragma unroll
      for (int L = 0; L < BM / 64; ++L)
        GLOAD16(A + offA[L] + t * 64, ldsA + d * (BM * 128) + L * 8192 + wid * 1024);
      #pragma unroll
      for (int L = 0; L < 4; ++L)
        GLOAD16(BT + offB[L] + t * 64, ldsB + d * 32768 + L * 8192 + wid * 1024);
    };

    stage(0, 0);
    stage(1, 1);

    #pragma unroll 1
    for (int t = 0; t < NT; ++t) {
      const int d = t & 1;
      asm volatile("s_waitcnt vmcnt(6)" ::: "memory");
      __builtin_amdgcn_s_barrier();
      __builtin_amdgcn_sched_barrier(0);

      const char* as = ldsA + d * (BM * 128);
      const char* bs = ldsB + d * 32768;
      #pragma unroll
      for (int kk = 0; kk < 2; ++kk) {
        bf16x8 af[MR], bfv[4];
        #pragma unroll
        for (int m = 0; m < MR; ++m)
          af[m] = *(const bf16x8*)(as +
              (wm * (BM / 2) + m * 16 + lr) * 128 + ((kk * 64 + kq * 16) ^ axor));
        #pragma unroll
        for (int n = 0; n < 4; ++n)
          bfv[n] = *(const bf16x8*)(bs +
              (wn * 64 + n * 16 + lr) * 128 + ((kk * 64 + kq * 16) ^ axor));
        #pragma unroll
        for (int m = 0; m < MR; ++m)
          #pragma unroll
          for (int n = 0; n < 4; ++n)
            acc[m][n] = mfma16(af[m], bfv[n], acc[m][n]);
      }

      asm volatile("s_waitcnt lgkmcnt(0)" ::: "memory");
      __builtin_amdgcn_s_barrier();
      __builtin_amdgcn_sched_barrier(0);
      const int ts = (t + 2 < NT) ? t + 2 : NT - 1;
      stage(ts, d);
    }
  }

  #pragma unroll
  for (int m = 0; m < MR; ++m) {
    #pragma unroll
    for (int n = 0; n < 4; ++n) {
      const int r0 = brow + wm * (BM / 2) + m * 16 + kq * 4;
      const int c  = bcol + wn * 64 + n * 16 + lr;
      if constexpr (MODE == 4) {
        if (c < 1024) {
          #pragma unroll
          for (int e = 0; e < 4; ++e)
            ((unsigned short*)Cout)[(size_t)(r0 + e) * 1024 + c] = f2bf(acc[m][n][e]);
        } else {
          const int cc = c - 1024;
          const int bq = r0 >> 10;
          const int tok = r0 & 1023;
          ushort4 pk;
          pk.x = f2bf(acc[m][n][0]); pk.y = f2bf(acc[m][n][1]);
          pk.z = f2bf(acc[m][n][2]); pk.w = f2bf(acc[m][n][3]);
          *(ushort4*)((unsigned short*)Cout2 + ((size_t)bq * 1024 + cc) * 1024 + tok) = pk;
        }
      } else if constexpr (MODE == 5) {
        unsigned short* o = (kh == 0) ? (unsigned short*)Cout : (unsigned short*)Cout2;
        #pragma unroll
        for (int e = 0; e < 4; ++e)
          o[(size_t)(r0 + e) * Ni + c] = f2bf(acc[m][n][e]);
      } else {
        const float bv = (MODE == 2 || MODE == 3) ? bias[c] : 0.0f;
        #pragma unroll
        for (int e = 0; e < 4; ++e) {
          float v = acc[m][n][e] + bv;
          if (MODE == 2) v = fmaxf(v, 0.0f);
          if (MODE == 0 || MODE == 2)
            ((unsigned short*)Cout)[(size_t)(r0 + e) * Ni + c] = f2bf(v);
          else
            ((float*)Cout)[(size_t)(r0 + e) * Ni + c] = v;
        }
      }
    }
  }
}

template <int BM, int MODE, int KS = 1>
__global__ __launch_bounds__(512, 2) void gemm256(
    const unsigned short* __restrict__ A, const unsigned short* __restrict__ BT,
    const float* __restrict__ bias, void* __restrict__ Cout, void* __restrict__ Cout2,
    int Ni, int Ki, int nbx) {
  constexpr int ABYTES = 2 * BM * 64 * 2;
  __shared__ char lds[ABYTES + 65536];
  gemm_body<BM, MODE, KS>(lds, lds + ABYTES, A, BT, bias, Cout, Cout2,
                          Ni, Ki, nbx, (int)blockIdx.x, (int)gridDim.x);
}

// ---- merged QKV projections: blocks [0,256) = KV (BM=256 MODE4),
//      blocks [256,512) = Q (BM=128 MODE0). One dispatch packs the machine.
__global__ __launch_bounds__(512, 2) void qkv_k(
    const unsigned short* __restrict__ hb, const unsigned short* __restrict__ hab,
    const unsigned short* __restrict__ wqt, const unsigned short* __restrict__ wkvt,
    unsigned short* __restrict__ qb, unsigned short* __restrict__ kb,
    unsigned short* __restrict__ vTb) {
  __shared__ char lds[131072];
  if (blockIdx.x < 256)
    gemm_body<256, 4, 1>(lds, lds + 65536, hab, wkvt, nullptr, kb, vTb,
                         2048, 1024, 8, (int)blockIdx.x, 256);
  else
    gemm_body<128, 0, 1>(lds, lds + 32768, hb, wqt, nullptr, qb, nullptr,
                         1024, 1024, 4, (int)blockIdx.x - 256, 256);
}

// ---------------- flash attention v4 (R17-proven): 128 q-rows/block ----------
// Swapped QK^T, lane-local softmax, cvt_pk packed P, swizzled LDS, dbuf K/V^T,
// counted vmcnt(2), setprio around MFMA clusters. grid (bh=128, qb=8).
__global__ __launch_bounds__(512, 6) void attn_k(
    const unsigned short* __restrict__ q, const unsigned short* __restrict__ k,
    const unsigned short* __restrict__ vT, unsigned short* __restrict__ ctx) {
  __shared__ unsigned short Ks[2][64 * 64];
  __shared__ unsigned short Vt[2][64 * 64];
  __shared__ unsigned short Ps[8][16 * 64];
  const int tid = threadIdx.x;
  const int lane = tid & 63;
  const int wid = tid >> 6;
  const int bh = blockIdx.x;                  // x = bh -> XCD affinity for K/V
  const int b = bh >> 4, h = bh & 15;
  const int qrow0 = blockIdx.y * 128 + wid * 16;
  const size_t tokbase = (size_t)b * 1024;
  const int lr = lane & 15, kq = lane >> 4;

  const int srow = tid >> 3;
  const int scol = ((tid & 7) * 8) ^ ((srow & 7) << 3);
  const unsigned short* kg = k + (tokbase + srow) * 1024 + h * 64 + scol;
  const unsigned short* vg = vT + ((size_t)(b * 16 + h) * 64 + srow) * 1024 + scol;
  const int ldst = tid * 16;

  auto stage = [&](int kt, int d) {
    GLOAD16(kg + (size_t)kt * 64 * 1024, (char*)Ks[d] + ldst);
    GLOAD16(vg + kt * 64, (char*)Vt[d] + ldst);
  };

  bf16x8 aq[2];
  {
    const unsigned short* qp = q + (tokbase + qrow0 + lr) * DD + h * 64 + kq * 8;
    aq[0] = *(const bf16x8*)qp;
    aq[1] = *(const bf16x8*)(qp + 32);
  }

  float l_acc = 0.f;
  f32x4 acc[4] = {};
  const float C = 0.125f * 1.4426950408889634f;
  const unsigned swp = (unsigned)((lr & 7) << 4);
  const unsigned pbase = (unsigned)(lr * 128);

  stage(0, 0);
  stage(1, 1);

  #pragma unroll 2
  for (int kt = 0; kt < 16; ++kt) {
    const int d = kt & 1;
    asm volatile("s_waitcnt vmcnt(2)" ::: "memory");
    __builtin_amdgcn_s_barrier();
    __builtin_amdgcn_sched_barrier(0);

    f32x4 sv[4] = {};
    __builtin_amdgcn_s_setprio(1);
    #pragma unroll
    for (int jb = 0; jb < 4; ++jb)
      #pragma unroll
      for (int ks = 0; ks < 2; ++ks) {
        int row = jb * 16 + lr;
        bf16x8 ak = *(const bf16x8*)((const char*)Ks[d] +
            row * 128 + ((ks * 64 + kq * 16) ^ ((row & 7) << 4)));
        sv[jb] = mfma16(ak, aq[ks], sv[jb]);
      }
    __builtin_amdgcn_s_setprio(0);

    #pragma unroll
    for (int jb = 0; jb < 4; ++jb) {
      float p0 = exp2f(sv[jb][0] * C);
      float p1 = exp2f(sv[jb][1] * C);
      float p2 = exp2f(sv[jb][2] * C);
      float p3 = exp2f(sv[jb][3] * C);
      l_acc += (p0 + p1) + (p2 + p3);
      uint2 w;
      w.x = cvtpk_bf16(p0, p1);
      w.y = cvtpk_bf16(p2, p3);
      unsigned off = pbase + (((unsigned)(jb * 32 + kq * 8)) ^ swp);
      *(uint2*)((char*)Ps[wid] + off) = w;
    }

    __builtin_amdgcn_s_setprio(1);
    #pragma unroll
    for (int ks = 0; ks < 2; ++ks) {
      bf16x8 ap = *(const bf16x8*)((const char*)Ps[wid] +
          lr * 128 + ((ks * 64 + kq * 16) ^ ((lr & 7) << 4)));
      #pragma unroll
      for (int db = 0; db < 4; ++db) {
        int dd = db * 16 + lr;
        bf16x8 bv = *(const bf16x8*)((const char*)Vt[d] +
            dd * 128 + ((ks * 64 + kq * 16) ^ ((dd & 7) << 4)));
        acc[db] = mfma16(bv, ap, acc[db]);
      }
    }
    __builtin_amdgcn_s_setprio(0);

    asm volatile("s_waitcnt lgkmcnt(0)" ::: "memory");
    __builtin_amdgcn_s_barrier();
    __builtin_amdgcn_sched_barrier(0);
    const int ts = (kt + 2 < 16) ? kt + 2 : 15;
    stage(ts, d);
  }

  float l = l_acc + __shfl_xor(l_acc, 16);
  l += __shfl_xor(l, 32);
  const float inv = 1.0f / l;
  unsigned short* cp = ctx + (tokbase + qrow0 + lr) * DD + h * 64 + kq * 4;
  #pragma unroll
  for (int db = 0; db < 4; ++db) {
    ushort4 o;
    o.x = f2bf(acc[db][0] * inv);
    o.y = f2bf(acc[db][1] * inv);
    o.z = f2bf(acc[db][2] * inv);
    o.w = f2bf(acc[db][3] * inv);
    *(ushort4*)(cp + db * 16) = o;
  }
}

// ---------------- LayerNorm(bf16 a + bf16 b) -> bf16 out ---------------------
__global__ __launch_bounds__(256) void ln_add_bb_k(
    const unsigned short* __restrict__ a, const unsigned short* __restrict__ b,
    const float* __restrict__ gamma, const float* __restrict__ beta,
    unsigned short* __restrict__ outb) {
  int row = blockIdx.x;
  int tid = threadIdx.x;
  size_t base = (size_t)row * 1024 + tid * 4;
  ushort4 va = *(const ushort4*)(a + base);
  ushort4 vb = *(const ushort4*)(b + base);
  float x[4] = {bf2f(va.x) + bf2f(vb.x), bf2f(va.y) + bf2f(vb.y),
                bf2f(va.z) + bf2f(vb.z), bf2f(va.w) + bf2f(vb.w)};
  float s = x[0] + x[1] + x[2] + x[3];
  float sq = x[0] * x[0] + x[1] * x[1] + x[2] * x[2] + x[3] * x[3];
  #pragma unroll
  for (int mk = 1; mk < 64; mk <<= 1) {
    s += __shfl_xor(s, mk);
    sq += __shfl_xor(sq, mk);
  }
  __shared__ float red[8];
  int wid = tid >> 6, lane = tid & 63;
  if (lane == 0) { red[wid] = s; red[4 + wid] = sq; }
  __syncthreads();
  s = red[0] + red[1] + red[2] + red[3];
  sq = red[4] + red[5] + red[6] + red[7];
  float mu = s * (1.0f / 1024.0f);
  float var = sq * (1.0f / 1024.0f) - mu * mu;
  float rs = rsqrtf(var + 1e-5f);
  float4 g = *(const float4*)(gamma + tid * 4);
  float4 be = *(const float4*)(beta + tid * 4);
  ushort4 ob;
  ob.x = f2bf((x[0] - mu) * rs * g.x + be.x);
  ob.y = f2bf((x[1] - mu) * rs * g.y + be.y);
  ob.z = f2bf((x[2] - mu) * rs * g.z + be.z);
  ob.w = f2bf((x[3] - mu) * rs * g.w + be.w);
  *(ushort4*)(outb + base) = ob;
}

// ---- LayerNorm(bf16 a + bf16 p0 + bf16 p1 + bias2) -> f32 out (FFN2 fused) --
__global__ __launch_bounds__(256) void ln3_k(
    const unsigned short* __restrict__ a, const unsigned short* __restrict__ p0,
    const unsigned short* __restrict__ p1, const float* __restrict__ b2,
    const float* __restrict__ gamma, const float* __restrict__ beta,
    float* __restrict__ outf) {
  int row = blockIdx.x;
  int tid = threadIdx.x;
  size_t base = (size_t)row * 1024 + tid * 4;
  ushort4 va = *(const ushort4*)(a + base);
  ushort4 v0 = *(const ushort4*)(p0 + base);
  ushort4 v1 = *(const ushort4*)(p1 + base);
  float4 bb = *(const float4*)(b2 + tid * 4);
  float x[4] = {bf2f(va.x) + bf2f(v0.x) + bf2f(v1.x) + bb.x,
                bf2f(va.y) + bf2f(v0.y) + bf2f(v1.y) + bb.y,
                bf2f(va.z) + bf2f(v0.z) + bf2f(v1.z) + bb.z,
                bf2f(va.w) + bf2f(v0.w) + bf2f(v1.w) + bb.w};
  float s = x[0] + x[1] + x[2] + x[3];
  float sq = x[0] * x[0] + x[1] * x[1] + x[2] * x[2] + x[3] * x[3];
  #pragma unroll
  for (int mk = 1; mk < 64; mk <<= 1) {
    s += __shfl_xor(s, mk);
    sq += __shfl_xor(sq, mk);
  }
  __shared__ float red[8];
  int wid = tid >> 6, lane = tid & 63;
  if (lane == 0) { red[wid] = s; red[4 + wid] = sq; }
  __syncthreads();
  s = red[0] + red[1] + red[2] + red[3];
  sq = red[4] + red[5] + red[6] + red[7];
  float mu = s * (1.0f / 1024.0f);
  float var = sq * (1.0f / 1024.0f) - mu * mu;
  float rs = rsqrtf(var + 1e-5f);
  float4 g = *(const float4*)(gamma + tid * 4);
  float4 be = *(const float4*)(beta + tid * 4);
  float4 o;
  o.x = (x[0] - mu) * rs * g.x + be.x;
  o.y = (x[1] - mu) * rs * g.y + be.y;
  o.z = (x[2] - mu) * rs * g.z + be.z;
  o.w = (x[3] - mu) * rs * g.w + be.w;
  *(float4*)(outf + base) = o;
}

// -----------------------------------------------------------------------------
extern "C" void kernel_launch(void* const* d_in, const int* in_sizes, int n_in,
                              void* d_out, int out_size, void* d_ws, size_t ws_size,
                              hipStream_t stream) {
  const float* h    = (const float*)d_in[0];
  const float* hall = (const float*)d_in[1];
  const float* Wq   = (const float*)d_in[2];
  const float* Wk   = (const float*)d_in[3];
  const float* Wv   = (const float*)d_in[4];
  const float* Wo   = (const float*)d_in[5];
  const float* W1   = (const float*)d_in[6];
  const float* b1   = (const float*)d_in[7];
  const float* W2   = (const float*)d_in[8];
  const float* b2   = (const float*)d_in[9];
  const float* g1   = (const float*)d_in[10];
  const float* be1  = (const float*)d_in[11];
  const float* g2   = (const float*)d_in[12];
  const float* be2  = (const float*)d_in[13];

  char* ws = (char*)d_ws;
  size_t off = 0;
  auto alloc = [&](size_t n) { size_t o = off; off += (n + 255) & ~(size_t)255; return o; };
  const size_t hb_o   = alloc((size_t)ROWS * DD * 2);
  const size_t hab_o  = alloc((size_t)ROWS * DD * 2);
  const size_t wqt_o  = alloc((size_t)DD * DD * 2);
  const size_t wkvt_o = alloc((size_t)DD * DD * 4);
  const size_t wot_o  = alloc((size_t)DD * DD * 2);
  const size_t w1t_o  = alloc((size_t)DD * FF * 2);
  const size_t w2t_o  = alloc((size_t)FF * DD * 2);
  const size_t qb_o   = alloc((size_t)ROWS * DD * 2);
  const size_t kb_o   = alloc((size_t)ROWS * DD * 2);
  const size_t vt_o   = alloc((size_t)ROWS * DD * 2);
  const size_t cx_o   = alloc((size_t)ROWS * DD * 2);
  const size_t h1b_o  = alloc((size_t)ROWS * DD * 2);
  const size_t fp1_o  = alloc((size_t)ROWS * DD * 2);

  unsigned short* hb   = (unsigned short*)(ws + hb_o);
  unsigned short* hab  = (unsigned short*)(ws + hab_o);
  unsigned short* wqt  = (unsigned short*)(ws + wqt_o);
  unsigned short* wkvt = (unsigned short*)(ws + wkvt_o);
  unsigned short* wot  = (unsigned short*)(ws + wot_o);
  unsigned short* w1t  = (unsigned short*)(ws + w1t_o);
  unsigned short* w2t  = (unsigned short*)(ws + w2t_o);
  unsigned short* qb   = (unsigned short*)(ws + qb_o);
  unsigned short* kb   = (unsigned short*)(ws + kb_o);
  unsigned short* vTb  = (unsigned short*)(ws + vt_o);
  unsigned short* cxb  = (unsigned short*)(ws + cx_o);
  unsigned short* h1b  = (unsigned short*)(ws + h1b_o);
  unsigned short* fp1b = (unsigned short*)(ws + fp1_o);
  // aliases (lifetime-disjoint):
  unsigned short* attn_ob = (unsigned short*)(ws + hab_o); // hab dead after KV-proj
  unsigned short* fp0b    = (unsigned short*)(ws + hb_o);  // hb dead after LN1
  unsigned short* ff1     = (unsigned short*)(ws + qb_o);  // 64MB over qb+kb+vT+cx
  float*          outf    = (float*)d_out;

  // 1. prep: casts + all weight transposes (one launch, 64x64 tiles)
  prep_k<<<dim3(16384 + 3072), 256, 0, stream>>>(
      h, hall, Wq, Wk, Wv, Wo, W1, W2, hb, hab, wqt, wkvt, wot, w1t, w2t);

  // 2. merged projections: KV (blocks 0-255) + Q (blocks 256-511)
  qkv_k<<<dim3(512), 512, 0, stream>>>(hb, hab, wqt, wkvt, qb, kb, vTb);

  // 3. attention (grid x = bh for XCD-affine K/V reuse; 128 q-rows/block)
  attn_k<<<dim3(128, 8), 512, 0, stream>>>(qb, kb, vTb, cxb);

  // 4. output projection (bf16 out over dead hab), then LN1 -> h1b (bf16 only)
  gemm256<128, 0><<<dim3(256), 512, 0, stream>>>(cxb, wot, nullptr, attn_ob, nullptr, DD, DD, 4);
  ln_add_bb_k<<<ROWS, 256, 0, stream>>>(hb, attn_ob, g1, be1, h1b);

  // 5. FFN: FFN1 direct; FFN2 split-K x2, both halves bf16 (bias in LN2)
  gemm256<256, 2>   <<<dim3(512), 512, 0, stream>>>(h1b, w1t, b1, ff1, nullptr, FF, DD, 16);
  gemm256<256, 5, 2><<<dim3(256), 512, 0, stream>>>(ff1, w2t, nullptr, fp0b, fp1b, DD, FF, 4);

  // 6. LN2: out = LN(h1b + ff2_p0 + ff2_p1 + b2)
  ln3_k<<<ROWS, 256, 0, stream>>>(h1b, fp0b, fp1b, b2, g2, be2, outf);
}